// Round 5
// baseline (532.807 us; speedup 1.0000x reference)
//
#include <hip/hip_runtime.h>
#include <math.h>

#define F_ 48
#define C_ 128
#define HW 16384
#define SCALE_C 0.999f
#define TPB 256

typedef __attribute__((ext_vector_type(8))) short short8;
typedef __attribute__((ext_vector_type(4))) float floatx4;
typedef __attribute__((ext_vector_type(2))) float v2;
typedef __attribute__((ext_vector_type(2))) unsigned int uint2v;

// ---- ws layout ----
// ushort region:
//   P1 frags: [b(2)][hl(2)][mt(12)][ks(4)][lane(64)][j(8)]  = 98304 ushorts
//   P2 frags: [b(2)][hl(2)][cmt(8)][ks(6)][lane(64)][j(8)]  = 98304 ushorts
// float region at float offset 98304:
#define P1_U 0
#define P2_U 98304
#define QEQN_F 98304              // [48][32] pair-interleaved (see setup)
#define MISC_F (QEQN_F + 1536)    // eps_e, invden
// LDS strides (ushort units for X/ACT): dword stride mod 32 == 4 -> conflict-free
#define XS 136
#define AS 200
#define QS 36                     // sQ float stride

__device__ __forceinline__ unsigned short f2bf(float f) {     // RTNE
    unsigned u = __float_as_uint(f);
    unsigned r = u + 0x7fffu + ((u >> 16) & 1u);
    return (unsigned short)(r >> 16);
}
__device__ __forceinline__ float bf2f(unsigned short h) {
    return __uint_as_float(((unsigned)h) << 16);
}

// ---------------- merged setup ----------------
__global__ void setup_all(const float* __restrict__ sigma,
                          const float* __restrict__ Qp,
                          const float* __restrict__ taus_p,
                          const float* __restrict__ lamb,
                          const float* __restrict__ eps_om,
                          const float* __restrict__ mw1, const float* __restrict__ mb1,
                          const float* __restrict__ mw2, const float* __restrict__ mb2,
                          const float* __restrict__ mw3, const float* __restrict__ mb3,
                          const float* __restrict__ Wf,
                          float* __restrict__ wsf)
{
    __shared__ float sInv[2][F_];
    __shared__ float sLam[2][F_];
    const int tid = threadIdx.x;
    unsigned short* wsu = (unsigned short*)wsf;

    // every block computes the tiny scaling MLP into LDS (needed for packing)
    if (tid >= 48 && tid < 50) {
        const int b = tid - 48;
        float lamb_e = expf(lamb[0]);
        float sg = sigma[b];
        float t = sg * 20.0f - 2.0f;
        float h1[F_], h2[F_];
        for (int j = 0; j < F_; ++j) h1[j] = fmaxf(t * mw1[j] + mb1[j], 0.0f);
        for (int j = 0; j < F_; ++j) {
            float s = mb2[j];
            for (int k = 0; k < F_; ++k) s += h1[k] * mw2[k * F_ + j];
            h2[j] = fmaxf(s, 0.0f);
        }
        for (int j = 0; j < F_; ++j) {
            float s = mb3[j];
            for (int k = 0; k < F_; ++k) s += h2[k] * mw3[k * F_ + j];
            float sc = fmaxf(s * 0.05f + sg, 0.0f) + 1e-9f;
            sInv[b][j] = 1.0f / sc;
            sLam[b][j] = lamb_e * sc;
        }
    }
    // block 0: activation params (pair-interleaved) + misc
    if (blockIdx.x == 0) {
        if (tid < F_) {
            const int f = tid;
            float Qm[4][4];
            for (int g = 0; g < 4; ++g) {
                float s = 0.f;
                for (int l = 0; l < 4; ++l) s += fabsf(Qp[f * 16 + g * 4 + l]);
                float d = fmaxf(s, 1.0f);
                for (int l = 0; l < 4; ++l) Qm[g][l] = Qp[f * 16 + g * 4 + l] / d;
            }
            double A[4][4];
            for (int i = 0; i < 4; ++i)
                for (int j = 0; j < 4; ++j) {
                    double s = 0.0;
                    for (int g = 0; g < 4; ++g) s += (double)Qm[g][i] * (double)Qm[g][j];
                    A[i][j] = s;
                }
            double M[4][4];
            for (int i = 0; i < 4; ++i) for (int j = 0; j < 4; ++j) M[i][j] = A[i][j];
            for (int it = 0; it < 30; ++it) {
                double T[4][4]; double mx = 0.0;
                for (int i = 0; i < 4; ++i)
                    for (int j = 0; j < 4; ++j) {
                        double s = 0.0;
                        for (int k = 0; k < 4; ++k) s += M[i][k] * M[k][j];
                        T[i][j] = s;
                        double a = fabs(s); if (a > mx) mx = a;
                    }
                if (mx < 1e-300) break;
                double inv = 1.0 / mx;
                for (int i = 0; i < 4; ++i) for (int j = 0; j < 4; ++j) M[i][j] = T[i][j] * inv;
            }
            int jb = 0; double bn = -1.0;
            for (int j = 0; j < 4; ++j) {
                double nn = 0.0;
                for (int i = 0; i < 4; ++i) nn += M[i][j] * M[i][j];
                if (nn > bn) { bn = nn; jb = j; }
            }
            double v[4]; for (int i = 0; i < 4; ++i) v[i] = M[i][jb];
            double Av[4];
            for (int i = 0; i < 4; ++i) {
                double s = 0.0;
                for (int j = 0; j < 4; ++j) s += A[i][j] * v[j];
                Av[i] = s;
            }
            double vv = 0.0, vav = 0.0;
            for (int i = 0; i < 4; ++i) { vv += v[i] * v[i]; vav += v[i] * Av[i]; }
            float lamf = (float)((vv > 0.0) ? (vav / vv) : 0.0);
            float tau = expf(fmaxf(taus_p[f], 0.0f));
            float qsv = SCALE_C / tau;
            // pair-interleaved: floats [4g..4g+3] = qe[0][g],qe[1][g],qe[2][g],qe[3][g]
            //                   floats [16+4g..] = qn[g][0..3]
            for (int g = 0; g < 4; ++g) {
                for (int l = 0; l < 4; ++l)
                    wsf[QEQN_F + f * 32 + 4 * g + l] = qsv * Qm[l][g] / lamf;
                for (int l = 0; l < 4; ++l)
                    wsf[QEQN_F + f * 32 + 16 + 4 * g + l] = SCALE_C * Qm[g][l];
            }
        }
        if (tid == 50) {
            float lamb_e = expf(lamb[0]);
            float eps_e = expf(eps_om[0]);
            wsf[MISC_F + 0] = eps_e;
            wsf[MISC_F + 1] = 1.0f / (1.0f + lamb_e * (1.0f + eps_e));
        }
    }
    __syncthreads();

    // grid-stride fragment packing
    for (int i = blockIdx.x * TPB + tid; i < 49152; i += gridDim.x * TPB) {
        if (i < 24576) {
            int j = i & 7, lane = (i >> 3) & 63;
            int t = i >> 9;
            int ks = t & 3, mt = t >> 2;
            int m = lane & 15, q = lane >> 4;
            int r = mt * 16 + m;
            int c = ks * 32 + q * 8 + j;
            int f = r >> 2, g = r & 3;
            float w = Wf[(g * F_ + f) * C_ + c];
#pragma unroll
            for (int b = 0; b < 2; ++b) {
                float v = w * sInv[b][f];
                unsigned short h = (unsigned short)(__float_as_uint(v) >> 16);
                float lo = v - bf2f(h);
                unsigned short l = (unsigned short)(__float_as_uint(lo) >> 16);
                wsu[P1_U + ((((b * 2 + 0) * 12 + mt) * 4 + ks) * 64 + lane) * 8 + j] = h;
                wsu[P1_U + ((((b * 2 + 1) * 12 + mt) * 4 + ks) * 64 + lane) * 8 + j] = l;
            }
        } else {
            int ii = i - 24576;
            int j = ii & 7, lane = (ii >> 3) & 63;
            int t = ii >> 9;
            int ks = t % 6, cmt = t / 6;
            int m = lane & 15, q = lane >> 4;
            int cch = cmt * 16 + m;
            int r = ks * 32 + q * 8 + j;
            int f = r >> 2, g = r & 3;
            float w = Wf[(g * F_ + f) * C_ + cch];
#pragma unroll
            for (int b = 0; b < 2; ++b) {
                float v = w * sLam[b][f];
                unsigned short h = (unsigned short)(__float_as_uint(v) >> 16);
                float lo = v - bf2f(h);
                unsigned short l = (unsigned short)(__float_as_uint(lo) >> 16);
                wsu[P2_U + ((((b * 2 + 0) * 8 + cmt) * 6 + ks) * 64 + lane) * 8 + j] = h;
                wsu[P2_U + ((((b * 2 + 1) * 8 + cmt) * 6 + ks) * 64 + lane) * 8 + j] = l;
            }
        }
    }
}

__device__ __forceinline__ void proj4(const float v[4], float o[4]) {
    float a0 = fabsf(v[0]), a1 = fabsf(v[1]), a2 = fabsf(v[2]), a3 = fabsf(v[3]);
    float sum = a0 + a1 + a2 + a3;
    float t0 = fmaxf(a0, a1), u0 = fminf(a0, a1);
    float t1 = fmaxf(a2, a3), u1 = fminf(a2, a3);
    float s0 = fmaxf(t0, t1), m0 = fminf(t0, t1);
    float m1 = fmaxf(u0, u1), s3 = fminf(u0, u1);
    float s1 = fmaxf(m1, m0), s2 = fminf(m1, m0);
    float c2 = s0 + s1, c3 = c2 + s2, c4 = c3 + s3;
    float th = s0 - 1.0f, rh = 1.0f;
    if (s1 * 2.0f > c2 - 1.0f) { th = c2 - 1.0f; rh = 2.0f; }
    if (s2 * 3.0f > c3 - 1.0f) { th = c3 - 1.0f; rh = 3.0f; }
    if (s3 * 4.0f > c4 - 1.0f) { th = c4 - 1.0f; rh = 4.0f; }
    float theta = fmaxf(th / rh, 0.0f);
    bool inside = (sum <= 1.0f);
#pragma unroll
    for (int g = 0; g < 4; ++g) {
        float ag = fabsf(v[g]);
        float pg = copysignf(fmaxf(ag - theta, 0.0f), v[g]);
        o[g] = inside ? v[g] : pg;
    }
}

__device__ __forceinline__ v2 fma2(v2 a, v2 b, v2 c) {
    return __builtin_elementwise_fma(a, b, c);
}

// split fp32 pair -> (packed hi bf16x2, packed lo bf16x2), truncation (exact pair)
__device__ __forceinline__ void split2(v2 nx, unsigned& hp, unsigned& lp) {
    hp = __builtin_amdgcn_perm(__float_as_uint(nx.y), __float_as_uint(nx.x), 0x07060302u);
    v2 hif = {__uint_as_float(__float_as_uint(nx.x) & 0xffff0000u),
              __uint_as_float(__float_as_uint(nx.y) & 0xffff0000u)};
    v2 lo = nx - hif;
    lp = __builtin_amdgcn_perm(__float_as_uint(lo.y), __float_as_uint(lo.x), 0x07060302u);
}

// ---------------- main ----------------
__global__ __launch_bounds__(TPB, 4) void mfoe_main(
    const float* __restrict__ xnoisy,
    const float* __restrict__ wsf,
    float* __restrict__ out,
    const int* __restrict__ n_iter_p)
{
    __shared__ __align__(16) unsigned short sXH[32 * XS];
    __shared__ __align__(16) unsigned short sXL[32 * XS];
    __shared__ __align__(16) unsigned short sACT[32 * AS];
    __shared__ __align__(16) float sQ[F_ * QS];

    const int tid = threadIdx.x;
    const int lane = tid & 63;
    const int wv = __builtin_amdgcn_readfirstlane(tid >> 6);
    const int n = lane & 15;
    const int q = lane >> 4;
    const int blk = blockIdx.x;
    const int b = blk >> 9;
    const int pix0 = (blk & 511) << 5;

    const float* __restrict__ xin = xnoisy + b * (C_ * HW) + pix0;
    float* __restrict__ oimg = out + b * (C_ * HW) + pix0;
    const unsigned short* __restrict__ wsu = (const unsigned short*)wsf;
    const int niter = *n_iter_p;

    if (niter == 0) {
        for (int i = tid; i < C_ * 32; i += TPB) {
            int p = i & 31, c = i >> 5;
            oimg[c * HW + p] = xin[c * HW + p];
        }
        return;
    }

    // owner-layout x in registers (fp32, exact): 4 jobs x 4 channels x 1 pixel
    v2 xr2[8], xn2[8];
#pragma unroll
    for (int j = 0; j < 4; ++j) {
        int jw = wv * 4 + j, cmt = jw >> 1, nt = jw & 1;
        int p = nt * 16 + n;
#pragma unroll
        for (int r = 0; r < 2; ++r) {
            int c = cmt * 16 + q * 4 + 2 * r;
            v2 t = {xin[c * HW + p], xin[(c + 1) * HW + p]};
            xn2[j * 2 + r] = t;
            xr2[j * 2 + r] = t;
        }
    }
    // stage activation params
    for (int i = tid; i < F_ * 32; i += TPB)
        sQ[(i >> 5) * QS + (i & 31)] = wsf[QEQN_F + i];

    // initial x split-write to LDS
#pragma unroll
    for (int j = 0; j < 4; ++j) {
        int jw = wv * 4 + j, cmt = jw >> 1, nt = jw & 1;
        int p = nt * 16 + n;
        int cb = cmt * 16 + q * 4;
        unsigned h01, l01, h23, l23;
        split2(xr2[j * 2 + 0], h01, l01);
        split2(xr2[j * 2 + 1], h23, l23);
        *(uint2v*)&sXH[p * XS + cb] = (uint2v){h01, h23};
        *(uint2v*)&sXL[p * XS + cb] = (uint2v){l01, l23};
    }

    const float eps_e = wsf[MISC_F + 0];
    const float invden = wsf[MISC_F + 1];

    for (int it = 0; it < niter; ++it) {
        __syncthreads();   // x (and first-iter sQ) ready
        // ---- pass 1: 3 m-tiles per wave, nt inner (param reuse)
#pragma unroll 1
        for (int jj = 0; jj < 3; ++jj) {
            const int mt = wv * 3 + jj;
            const int f = mt * 4 + q;
            floatx4 qf[8];
#pragma unroll
            for (int k = 0; k < 8; ++k)
                qf[k] = *(const floatx4*)&sQ[f * QS + 4 * k];
            const short8* aHp = (const short8*)(wsu + P1_U + (((b * 2 + 0) * 12 + mt) * 4) * 512 + lane * 8);
            const short8* aLp = (const short8*)(wsu + P1_U + (((b * 2 + 1) * 12 + mt) * 4) * 512 + lane * 8);
#pragma unroll
            for (int nt = 0; nt < 2; ++nt) {
                const int p = nt * 16 + n;
                floatx4 acc = (floatx4){0.f, 0.f, 0.f, 0.f};
#pragma unroll
                for (int ks = 0; ks < 4; ++ks) {
                    short8 aH = aHp[ks * 64];
                    short8 aL = aLp[ks * 64];
                    short8 bH = *(const short8*)&sXH[p * XS + ks * 32 + q * 8];
                    short8 bL = *(const short8*)&sXL[p * XS + ks * 32 + q * 8];
                    acc = __builtin_amdgcn_mfma_f32_16x16x32_bf16(aH, bH, acc, 0, 0, 0);
                    acc = __builtin_amdgcn_mfma_f32_16x16x32_bf16(aH, bL, acc, 0, 0, 0);
                    acc = __builtin_amdgcn_mfma_f32_16x16x32_bf16(aL, bH, acc, 0, 0, 0);
                }
                // ---- activation in D-regs (lane owns f, pixel p)
                float v[4] = {acc[0], acc[1], acc[2], acc[3]};
                float pv[4]; proj4(v, pv);
                v2 y01 = qf[0].xy * v[0];
                v2 y23 = qf[0].zw * v[0];
                y01 = fma2(qf[1].xy, (v2){v[1], v[1]}, y01);
                y23 = fma2(qf[1].zw, (v2){v[1], v[1]}, y23);
                y01 = fma2(qf[2].xy, (v2){v[2], v[2]}, y01);
                y23 = fma2(qf[2].zw, (v2){v[2], v[2]}, y23);
                y01 = fma2(qf[3].xy, (v2){v[3], v[3]}, y01);
                y23 = fma2(qf[3].zw, (v2){v[3], v[3]}, y23);
                float y[4] = {y01.x, y01.y, y23.x, y23.y};
                float py[4]; proj4(y, py);
                float m2[4];
#pragma unroll
                for (int g = 0; g < 4; ++g) m2[g] = fmaf(eps_e, y[g], py[g]);
                v2 g01 = qf[4].xy * m2[0];
                v2 g23 = qf[4].zw * m2[0];
                g01 = fma2(qf[5].xy, (v2){m2[1], m2[1]}, g01);
                g23 = fma2(qf[5].zw, (v2){m2[1], m2[1]}, g23);
                g01 = fma2(qf[6].xy, (v2){m2[2], m2[2]}, g01);
                g23 = fma2(qf[6].zw, (v2){m2[2], m2[2]}, g23);
                g01 = fma2(qf[7].xy, (v2){m2[3], m2[3]}, g01);
                g23 = fma2(qf[7].zw, (v2){m2[3], m2[3]}, g23);
                float a0 = fmaf(eps_e, v[0], pv[0]) - g01.x;
                float a1 = fmaf(eps_e, v[1], pv[1]) - g01.y;
                float a2 = fmaf(eps_e, v[2], pv[2]) - g23.x;
                float a3 = fmaf(eps_e, v[3], pv[3]) - g23.y;
                unsigned pk0 = ((unsigned)f2bf(a1) << 16) | f2bf(a0);
                unsigned pk1 = ((unsigned)f2bf(a3) << 16) | f2bf(a2);
                *(uint2v*)&sACT[p * AS + mt * 16 + q * 4] = (uint2v){pk0, pk1};
            }
        }
        __syncthreads();   // act ready (also: all pass-1 x reads done)
        // ---- pass 2: full K=192 per job
        floatx4 acc2[4];
#pragma unroll
        for (int j = 0; j < 4; ++j) acc2[j] = (floatx4){0.f, 0.f, 0.f, 0.f};
#pragma unroll
        for (int j = 0; j < 4; ++j) {
            int jw = wv * 4 + j, cmt = jw >> 1, nt = jw & 1;
            int p = nt * 16 + n;
            const short8* a2H = (const short8*)(wsu + P2_U + (((b * 2 + 0) * 8 + cmt) * 6) * 512 + lane * 8);
            const short8* a2L = (const short8*)(wsu + P2_U + (((b * 2 + 1) * 8 + cmt) * 6) * 512 + lane * 8);
            floatx4 a = acc2[j];
#pragma unroll
            for (int ks = 0; ks < 6; ++ks) {
                short8 aH = a2H[ks * 64];
                short8 aL = a2L[ks * 64];
                short8 bA = *(const short8*)&sACT[p * AS + ks * 32 + q * 8];
                a = __builtin_amdgcn_mfma_f32_16x16x32_bf16(aH, bA, a, 0, 0, 0);
                a = __builtin_amdgcn_mfma_f32_16x16x32_bf16(aL, bA, a, 0, 0, 0);
            }
            acc2[j] = a;
        }
        // ---- update in registers; write next-x (bf16 hi/lo) to LDS
        const bool last = (it == niter - 1);
        const v2 dv = {invden, invden};
#pragma unroll
        for (int j = 0; j < 4; ++j) {
            int jw = wv * 4 + j, cmt = jw >> 1, nt = jw & 1;
            int p = nt * 16 + n;
            int cb = cmt * 16 + q * 4;
            unsigned hp[2], lp[2];
#pragma unroll
            for (int r = 0; r < 2; ++r) {
                v2 xr = xr2[j * 2 + r];
                v2 go = {acc2[j][2 * r], acc2[j][2 * r + 1]};
                v2 t = (xr - xn2[j * 2 + r]) + go;
                v2 nx = xr - t * dv;
                xr2[j * 2 + r] = nx;
                if (last) {
                    oimg[(cb + 2 * r) * HW + p] = nx.x;
                    oimg[(cb + 2 * r + 1) * HW + p] = nx.y;
                } else {
                    split2(nx, hp[r], lp[r]);
                }
            }
            if (!last) {
                *(uint2v*)&sXH[p * XS + cb] = (uint2v){hp[0], hp[1]};
                *(uint2v*)&sXL[p * XS + cb] = (uint2v){lp[0], lp[1]};
            }
        }
    }
}

extern "C" void kernel_launch(void* const* d_in, const int* in_sizes, int n_in,
                              void* d_out, int out_size, void* d_ws, size_t ws_size,
                              hipStream_t stream) {
    const float* x_noisy = (const float*)d_in[0];
    const float* sigma   = (const float*)d_in[1];
    const float* Qp      = (const float*)d_in[2];
    const float* taus_p  = (const float*)d_in[3];
    const float* lamb    = (const float*)d_in[4];
    const float* eps_om  = (const float*)d_in[5];
    const float* mw1     = (const float*)d_in[6];
    const float* mb1     = (const float*)d_in[7];
    const float* mw2     = (const float*)d_in[8];
    const float* mb2     = (const float*)d_in[9];
    const float* mw3     = (const float*)d_in[10];
    const float* mb3     = (const float*)d_in[11];
    const float* Wf      = (const float*)d_in[12];
    const int*   n_iter  = (const int*)d_in[13];
    float* out = (float*)d_out;
    float* ws  = (float*)d_ws;

    hipLaunchKernelGGL(setup_all, dim3(64), dim3(TPB), 0, stream,
                       sigma, Qp, taus_p, lamb, eps_om,
                       mw1, mb1, mw2, mb2, mw3, mb3, Wf, ws);
    hipLaunchKernelGGL(mfoe_main, dim3(1024), dim3(TPB), 0, stream,
                       x_noisy, ws, out, n_iter);
}

// Round 6
// 471.630 us; speedup vs baseline: 1.1297x; 1.1297x over previous
//
#include <hip/hip_runtime.h>
#include <math.h>

#define F_ 48
#define C_ 128
#define HW 16384
#define SCALE_C 0.999f
#define TPB 256

typedef __attribute__((ext_vector_type(8))) short short8;
typedef __attribute__((ext_vector_type(4))) float floatx4;
typedef __attribute__((ext_vector_type(2))) float v2;
typedef __attribute__((ext_vector_type(2))) unsigned int uint2v;

// ---- ws layout ----
// ushort region:
//   P1 frags: [b(2)][hl(2)][mt(12)][ks(4)][lane(64)][j(8)]  = 98304 ushorts
//   P2 frags: [b(2)][hl(2)][cmt(8)][ks(6)][lane(64)][j(8)]  = 98304 ushorts
// float region at float offset 98304:
#define P1_U 0
#define P2_U 98304
#define QEQN_F 98304              // [48][32] pair-interleaved
#define MISC_F (QEQN_F + 1536)    // eps_e, invden
// LDS strides (ushort units): dword stride mod 32 == 4 -> low conflicts, 16B aligned
#define XS 136
#define AS 200
#define QS 36                     // sQ float stride

__device__ __forceinline__ unsigned short f2bf(float f) {     // RTNE
    unsigned u = __float_as_uint(f);
    unsigned r = u + 0x7fffu + ((u >> 16) & 1u);
    return (unsigned short)(r >> 16);
}
__device__ __forceinline__ float bf2f(unsigned short h) {
    return __uint_as_float(((unsigned)h) << 16);
}

// ---------------- merged setup ----------------
__global__ void setup_all(const float* __restrict__ sigma,
                          const float* __restrict__ Qp,
                          const float* __restrict__ taus_p,
                          const float* __restrict__ lamb,
                          const float* __restrict__ eps_om,
                          const float* __restrict__ mw1, const float* __restrict__ mb1,
                          const float* __restrict__ mw2, const float* __restrict__ mb2,
                          const float* __restrict__ mw3, const float* __restrict__ mb3,
                          const float* __restrict__ Wf,
                          float* __restrict__ wsf)
{
    __shared__ float sInv[2][F_];
    __shared__ float sLam[2][F_];
    const int tid = threadIdx.x;
    unsigned short* wsu = (unsigned short*)wsf;

    if (tid >= 48 && tid < 50) {
        const int b = tid - 48;
        float lamb_e = expf(lamb[0]);
        float sg = sigma[b];
        float t = sg * 20.0f - 2.0f;
        float h1[F_], h2[F_];
        for (int j = 0; j < F_; ++j) h1[j] = fmaxf(t * mw1[j] + mb1[j], 0.0f);
        for (int j = 0; j < F_; ++j) {
            float s = mb2[j];
            for (int k = 0; k < F_; ++k) s += h1[k] * mw2[k * F_ + j];
            h2[j] = fmaxf(s, 0.0f);
        }
        for (int j = 0; j < F_; ++j) {
            float s = mb3[j];
            for (int k = 0; k < F_; ++k) s += h2[k] * mw3[k * F_ + j];
            float sc = fmaxf(s * 0.05f + sg, 0.0f) + 1e-9f;
            sInv[b][j] = 1.0f / sc;
            sLam[b][j] = lamb_e * sc;
        }
    }
    if (blockIdx.x == 0) {
        if (tid < F_) {
            const int f = tid;
            float Qm[4][4];
            for (int g = 0; g < 4; ++g) {
                float s = 0.f;
                for (int l = 0; l < 4; ++l) s += fabsf(Qp[f * 16 + g * 4 + l]);
                float d = fmaxf(s, 1.0f);
                for (int l = 0; l < 4; ++l) Qm[g][l] = Qp[f * 16 + g * 4 + l] / d;
            }
            double A[4][4];
            for (int i = 0; i < 4; ++i)
                for (int j = 0; j < 4; ++j) {
                    double s = 0.0;
                    for (int g = 0; g < 4; ++g) s += (double)Qm[g][i] * (double)Qm[g][j];
                    A[i][j] = s;
                }
            double M[4][4];
            for (int i = 0; i < 4; ++i) for (int j = 0; j < 4; ++j) M[i][j] = A[i][j];
            for (int it = 0; it < 30; ++it) {
                double T[4][4]; double mx = 0.0;
                for (int i = 0; i < 4; ++i)
                    for (int j = 0; j < 4; ++j) {
                        double s = 0.0;
                        for (int k = 0; k < 4; ++k) s += M[i][k] * M[k][j];
                        T[i][j] = s;
                        double a = fabs(s); if (a > mx) mx = a;
                    }
                if (mx < 1e-300) break;
                double inv = 1.0 / mx;
                for (int i = 0; i < 4; ++i) for (int j = 0; j < 4; ++j) M[i][j] = T[i][j] * inv;
            }
            int jb = 0; double bn = -1.0;
            for (int j = 0; j < 4; ++j) {
                double nn = 0.0;
                for (int i = 0; i < 4; ++i) nn += M[i][j] * M[i][j];
                if (nn > bn) { bn = nn; jb = j; }
            }
            double v[4]; for (int i = 0; i < 4; ++i) v[i] = M[i][jb];
            double Av[4];
            for (int i = 0; i < 4; ++i) {
                double s = 0.0;
                for (int j = 0; j < 4; ++j) s += A[i][j] * v[j];
                Av[i] = s;
            }
            double vv = 0.0, vav = 0.0;
            for (int i = 0; i < 4; ++i) { vv += v[i] * v[i]; vav += v[i] * Av[i]; }
            float lamf = (float)((vv > 0.0) ? (vav / vv) : 0.0);
            float tau = expf(fmaxf(taus_p[f], 0.0f));
            float qsv = SCALE_C / tau;
            // pair-interleaved: [4g+l] = qe[l][g]*qsv/lamf ; [16+4g+l] = qn[g][l]*SCALE
            for (int g = 0; g < 4; ++g) {
                for (int l = 0; l < 4; ++l)
                    wsf[QEQN_F + f * 32 + 4 * g + l] = qsv * Qm[l][g] / lamf;
                for (int l = 0; l < 4; ++l)
                    wsf[QEQN_F + f * 32 + 16 + 4 * g + l] = SCALE_C * Qm[g][l];
            }
        }
        if (tid == 50) {
            float lamb_e = expf(lamb[0]);
            float eps_e = expf(eps_om[0]);
            wsf[MISC_F + 0] = eps_e;
            wsf[MISC_F + 1] = 1.0f / (1.0f + lamb_e * (1.0f + eps_e));
        }
    }
    __syncthreads();

    for (int i = blockIdx.x * TPB + tid; i < 49152; i += gridDim.x * TPB) {
        if (i < 24576) {
            int j = i & 7, lane = (i >> 3) & 63;
            int t = i >> 9;
            int ks = t & 3, mt = t >> 2;
            int m = lane & 15, q = lane >> 4;
            int r = mt * 16 + m;
            int c = ks * 32 + q * 8 + j;
            int f = r >> 2, g = r & 3;
            float w = Wf[(g * F_ + f) * C_ + c];
#pragma unroll
            for (int b = 0; b < 2; ++b) {
                float v = w * sInv[b][f];
                unsigned short h = (unsigned short)(__float_as_uint(v) >> 16);
                float lo = v - bf2f(h);
                unsigned short l = (unsigned short)(__float_as_uint(lo) >> 16);
                wsu[P1_U + ((((b * 2 + 0) * 12 + mt) * 4 + ks) * 64 + lane) * 8 + j] = h;
                wsu[P1_U + ((((b * 2 + 1) * 12 + mt) * 4 + ks) * 64 + lane) * 8 + j] = l;
            }
        } else {
            int ii = i - 24576;
            int j = ii & 7, lane = (ii >> 3) & 63;
            int t = ii >> 9;
            int ks = t % 6, cmt = t / 6;
            int m = lane & 15, q = lane >> 4;
            int cch = cmt * 16 + m;
            int r = ks * 32 + q * 8 + j;
            int f = r >> 2, g = r & 3;
            float w = Wf[(g * F_ + f) * C_ + cch];
#pragma unroll
            for (int b = 0; b < 2; ++b) {
                float v = w * sLam[b][f];
                unsigned short h = (unsigned short)(__float_as_uint(v) >> 16);
                float lo = v - bf2f(h);
                unsigned short l = (unsigned short)(__float_as_uint(lo) >> 16);
                wsu[P2_U + ((((b * 2 + 0) * 8 + cmt) * 6 + ks) * 64 + lane) * 8 + j] = h;
                wsu[P2_U + ((((b * 2 + 1) * 8 + cmt) * 6 + ks) * 64 + lane) * 8 + j] = l;
            }
        }
    }
}

__device__ __forceinline__ void proj4(const float v[4], float o[4]) {
    float a0 = fabsf(v[0]), a1 = fabsf(v[1]), a2 = fabsf(v[2]), a3 = fabsf(v[3]);
    float sum = a0 + a1 + a2 + a3;
    float t0 = fmaxf(a0, a1), u0 = fminf(a0, a1);
    float t1 = fmaxf(a2, a3), u1 = fminf(a2, a3);
    float s0 = fmaxf(t0, t1), m0 = fminf(t0, t1);
    float m1 = fmaxf(u0, u1), s3 = fminf(u0, u1);
    float s1 = fmaxf(m1, m0), s2 = fminf(m1, m0);
    float c2 = s0 + s1, c3 = c2 + s2, c4 = c3 + s3;
    float th = s0 - 1.0f, rh = 1.0f;
    if (s1 * 2.0f > c2 - 1.0f) { th = c2 - 1.0f; rh = 2.0f; }
    if (s2 * 3.0f > c3 - 1.0f) { th = c3 - 1.0f; rh = 3.0f; }
    if (s3 * 4.0f > c4 - 1.0f) { th = c4 - 1.0f; rh = 4.0f; }
    float theta = fmaxf(th / rh, 0.0f);
    bool inside = (sum <= 1.0f);
#pragma unroll
    for (int g = 0; g < 4; ++g) {
        float ag = fabsf(v[g]);
        float pg = copysignf(fmaxf(ag - theta, 0.0f), v[g]);
        o[g] = inside ? v[g] : pg;
    }
}

__device__ __forceinline__ v2 fma2(v2 a, v2 b, v2 c) {
    return __builtin_elementwise_fma(a, b, c);
}

// split fp32 pair -> (packed hi bf16x2, packed lo bf16x2), truncation (pair-exactish)
__device__ __forceinline__ void split2(v2 nx, unsigned& hp, unsigned& lp) {
    hp = __builtin_amdgcn_perm(__float_as_uint(nx.y), __float_as_uint(nx.x), 0x07060302u);
    v2 hif = {__uint_as_float(__float_as_uint(nx.x) & 0xffff0000u),
              __uint_as_float(__float_as_uint(nx.y) & 0xffff0000u)};
    v2 lo = nx - hif;
    lp = __builtin_amdgcn_perm(__float_as_uint(lo.y), __float_as_uint(lo.x), 0x07060302u);
}

// ---------------- main: x in LDS (spill-free), 2 barriers/iter ----------------
__global__ __launch_bounds__(TPB, 4) void mfoe_main(
    const float* __restrict__ xnoisy,
    const float* __restrict__ wsf,
    float* __restrict__ out,
    const int* __restrict__ n_iter_p)
{
    __shared__ __align__(16) unsigned short sXH[32 * XS];
    __shared__ __align__(16) unsigned short sXL[32 * XS];
    __shared__ __align__(16) unsigned short sACT[32 * AS];
    __shared__ __align__(16) float sQ[F_ * QS];

    const int tid = threadIdx.x;
    const int lane = tid & 63;
    const int wv = __builtin_amdgcn_readfirstlane(tid >> 6);
    const int n = lane & 15;
    const int q = lane >> 4;
    const int blk = blockIdx.x;
    const int b = blk >> 9;
    const int pix0 = (blk & 511) << 5;

    const float* __restrict__ xin = xnoisy + b * (C_ * HW) + pix0;
    float* __restrict__ oimg = out + b * (C_ * HW) + pix0;
    const unsigned short* __restrict__ wsu = (const unsigned short*)wsf;
    const int niter = *n_iter_p;

    if (niter == 0) {
        for (int i = tid; i < C_ * 32; i += TPB) {
            int p = i & 31, c = i >> 5;
            oimg[c * HW + p] = xin[c * HW + p];
        }
        return;
    }

    // stage x -> LDS bf16 hi/lo (coalesced reads)
    for (int i = tid; i < C_ * 32; i += TPB) {
        int p = i & 31, c = i >> 5;
        float v = xin[c * HW + p];
        unsigned short h = (unsigned short)(__float_as_uint(v) >> 16);
        float lo = v - bf2f(h);
        sXH[p * XS + c] = h;
        sXL[p * XS + c] = (unsigned short)(__float_as_uint(lo) >> 16);
    }
    // stage activation params
    for (int i = tid; i < F_ * 32; i += TPB)
        sQ[(i >> 5) * QS + (i & 31)] = wsf[QEQN_F + i];

    // preload this thread's x_noisy values (update layout): [cl][nt][reg]
    float xnr[16];
#pragma unroll
    for (int cl = 0; cl < 2; ++cl) {
        int cmt = wv * 2 + cl;
#pragma unroll
        for (int nt = 0; nt < 2; ++nt) {
            int p = nt * 16 + n;
#pragma unroll
            for (int reg = 0; reg < 4; ++reg)
                xnr[(cl * 2 + nt) * 4 + reg] = xin[(cmt * 16 + q * 4 + reg) * HW + p];
        }
    }
    const float eps_e = wsf[MISC_F + 0];
    const float invden = wsf[MISC_F + 1];

    for (int it = 0; it < niter; ++it) {
        __syncthreads();   // x ready (and sQ on iter 0)
        // ---- pass 1: wave owns 3 m-tiles; fragments loaded once, used for both nt
#pragma unroll 1
        for (int jj = 0; jj < 3; ++jj) {
            const int mt = wv * 3 + jj;
            const short8* aHp = (const short8*)(wsu + P1_U + (((b * 2 + 0) * 12 + mt) * 4) * 512 + lane * 8);
            const short8* aLp = (const short8*)(wsu + P1_U + (((b * 2 + 1) * 12 + mt) * 4) * 512 + lane * 8);
            floatx4 acc[2];
            acc[0] = (floatx4){0.f, 0.f, 0.f, 0.f};
            acc[1] = (floatx4){0.f, 0.f, 0.f, 0.f};
#pragma unroll
            for (int ks = 0; ks < 4; ++ks) {
                short8 aH = aHp[ks * 64];
                short8 aL = aLp[ks * 64];
#pragma unroll
                for (int nt = 0; nt < 2; ++nt) {
                    const int p = nt * 16 + n;
                    short8 bH = *(const short8*)&sXH[p * XS + ks * 32 + q * 8];
                    short8 bL = *(const short8*)&sXL[p * XS + ks * 32 + q * 8];
                    acc[nt] = __builtin_amdgcn_mfma_f32_16x16x32_bf16(aH, bH, acc[nt], 0, 0, 0);
                    acc[nt] = __builtin_amdgcn_mfma_f32_16x16x32_bf16(aH, bL, acc[nt], 0, 0, 0);
                    acc[nt] = __builtin_amdgcn_mfma_f32_16x16x32_bf16(aL, bH, acc[nt], 0, 0, 0);
                }
            }
            // params loaded once per m-tile, used for both nt activations
            const int f = mt * 4 + q;
            floatx4 qf[8];
#pragma unroll
            for (int k = 0; k < 8; ++k)
                qf[k] = *(const floatx4*)&sQ[f * QS + 4 * k];
#pragma unroll
            for (int nt = 0; nt < 2; ++nt) {
                const int p = nt * 16 + n;
                float v[4] = {acc[nt][0], acc[nt][1], acc[nt][2], acc[nt][3]};
                float pv[4]; proj4(v, pv);
                v2 y01 = qf[0].xy * v[0];
                v2 y23 = qf[0].zw * v[0];
                y01 = fma2(qf[1].xy, (v2){v[1], v[1]}, y01);
                y23 = fma2(qf[1].zw, (v2){v[1], v[1]}, y23);
                y01 = fma2(qf[2].xy, (v2){v[2], v[2]}, y01);
                y23 = fma2(qf[2].zw, (v2){v[2], v[2]}, y23);
                y01 = fma2(qf[3].xy, (v2){v[3], v[3]}, y01);
                y23 = fma2(qf[3].zw, (v2){v[3], v[3]}, y23);
                float y[4] = {y01.x, y01.y, y23.x, y23.y};
                float py[4]; proj4(y, py);
                float m2[4];
#pragma unroll
                for (int g = 0; g < 4; ++g) m2[g] = fmaf(eps_e, y[g], py[g]);
                v2 g01 = qf[4].xy * m2[0];
                v2 g23 = qf[4].zw * m2[0];
                g01 = fma2(qf[5].xy, (v2){m2[1], m2[1]}, g01);
                g23 = fma2(qf[5].zw, (v2){m2[1], m2[1]}, g23);
                g01 = fma2(qf[6].xy, (v2){m2[2], m2[2]}, g01);
                g23 = fma2(qf[6].zw, (v2){m2[2], m2[2]}, g23);
                g01 = fma2(qf[7].xy, (v2){m2[3], m2[3]}, g01);
                g23 = fma2(qf[7].zw, (v2){m2[3], m2[3]}, g23);
                float a0 = fmaf(eps_e, v[0], pv[0]) - g01.x;
                float a1 = fmaf(eps_e, v[1], pv[1]) - g01.y;
                float a2 = fmaf(eps_e, v[2], pv[2]) - g23.x;
                float a3 = fmaf(eps_e, v[3], pv[3]) - g23.y;
                unsigned pk0 = ((unsigned)f2bf(a1) << 16) | f2bf(a0);
                unsigned pk1 = ((unsigned)f2bf(a3) << 16) | f2bf(a2);
                *(uint2v*)&sACT[p * AS + mt * 16 + q * 4] = (uint2v){pk0, pk1};
            }
        }
        __syncthreads();   // act ready; all pass-1 x reads done
        // ---- pass 2: wave owns 2 c-tiles; fragments loaded once per ks, both nt
        floatx4 acc2[4];
#pragma unroll
        for (int j = 0; j < 4; ++j) acc2[j] = (floatx4){0.f, 0.f, 0.f, 0.f};
#pragma unroll 1
        for (int cl = 0; cl < 2; ++cl) {
            const int cmt = wv * 2 + cl;
            const short8* a2H = (const short8*)(wsu + P2_U + (((b * 2 + 0) * 8 + cmt) * 6) * 512 + lane * 8);
            const short8* a2L = (const short8*)(wsu + P2_U + (((b * 2 + 1) * 8 + cmt) * 6) * 512 + lane * 8);
            floatx4 a0 = acc2[cl * 2 + 0];
            floatx4 a1 = acc2[cl * 2 + 1];
#pragma unroll
            for (int ks = 0; ks < 6; ++ks) {
                short8 aH = a2H[ks * 64];
                short8 aL = a2L[ks * 64];
                short8 bA0 = *(const short8*)&sACT[(0 * 16 + n) * AS + ks * 32 + q * 8];
                short8 bA1 = *(const short8*)&sACT[(1 * 16 + n) * AS + ks * 32 + q * 8];
                a0 = __builtin_amdgcn_mfma_f32_16x16x32_bf16(aH, bA0, a0, 0, 0, 0);
                a1 = __builtin_amdgcn_mfma_f32_16x16x32_bf16(aH, bA1, a1, 0, 0, 0);
                a0 = __builtin_amdgcn_mfma_f32_16x16x32_bf16(aL, bA0, a0, 0, 0, 0);
                a1 = __builtin_amdgcn_mfma_f32_16x16x32_bf16(aL, bA1, a1, 0, 0, 0);
            }
            acc2[cl * 2 + 0] = a0;
            acc2[cl * 2 + 1] = a1;
        }
        // ---- update: owner round-trip through LDS (no persistent x registers)
        const bool last = (it == niter - 1);
#pragma unroll
        for (int cl = 0; cl < 2; ++cl) {
            const int cmt = wv * 2 + cl;
#pragma unroll
            for (int nt = 0; nt < 2; ++nt) {
                const int j = cl * 2 + nt;
                const int p = nt * 16 + n;
                const int cb = cmt * 16 + q * 4;
                unsigned long long oh = *(const unsigned long long*)&sXH[p * XS + cb];
                unsigned long long ol = *(const unsigned long long*)&sXL[p * XS + cb];
                unsigned hp[2], lp[2];
#pragma unroll
                for (int r = 0; r < 2; ++r) {
                    v2 xo = {bf2f((unsigned short)(oh >> (32 * r))) +
                             bf2f((unsigned short)(ol >> (32 * r))),
                             bf2f((unsigned short)(oh >> (32 * r + 16))) +
                             bf2f((unsigned short)(ol >> (32 * r + 16)))};
                    v2 xnv = {xnr[j * 4 + 2 * r], xnr[j * 4 + 2 * r + 1]};
                    v2 go = {acc2[j][2 * r], acc2[j][2 * r + 1]};
                    v2 t = (xo - xnv) + go;
                    v2 nx = xo - t * (v2){invden, invden};
                    if (last) {
                        oimg[(cb + 2 * r) * HW + p] = nx.x;
                        oimg[(cb + 2 * r + 1) * HW + p] = nx.y;
                    } else {
                        split2(nx, hp[r], lp[r]);
                    }
                }
                if (!last) {
                    *(uint2v*)&sXH[p * XS + cb] = (uint2v){hp[0], hp[1]};
                    *(uint2v*)&sXL[p * XS + cb] = (uint2v){lp[0], lp[1]};
                }
            }
        }
    }
}

extern "C" void kernel_launch(void* const* d_in, const int* in_sizes, int n_in,
                              void* d_out, int out_size, void* d_ws, size_t ws_size,
                              hipStream_t stream) {
    const float* x_noisy = (const float*)d_in[0];
    const float* sigma   = (const float*)d_in[1];
    const float* Qp      = (const float*)d_in[2];
    const float* taus_p  = (const float*)d_in[3];
    const float* lamb    = (const float*)d_in[4];
    const float* eps_om  = (const float*)d_in[5];
    const float* mw1     = (const float*)d_in[6];
    const float* mb1     = (const float*)d_in[7];
    const float* mw2     = (const float*)d_in[8];
    const float* mb2     = (const float*)d_in[9];
    const float* mw3     = (const float*)d_in[10];
    const float* mb3     = (const float*)d_in[11];
    const float* Wf      = (const float*)d_in[12];
    const int*   n_iter  = (const int*)d_in[13];
    float* out = (float*)d_out;
    float* ws  = (float*)d_ws;

    hipLaunchKernelGGL(setup_all, dim3(64), dim3(TPB), 0, stream,
                       sigma, Qp, taus_p, lamb, eps_om,
                       mw1, mb1, mw2, mb2, mw3, mb3, Wf, ws);
    hipLaunchKernelGGL(mfoe_main, dim3(1024), dim3(TPB), 0, stream,
                       x_noisy, ws, out, n_iter);
}